// Round 6
// baseline (7682.759 us; speedup 1.0000x reference)
//
#include <hip/hip_runtime.h>

#define T_STEPS 2048
#define H       500
#define E       300
#define HP      512      // padded h stride (floats)
#define XPT     2048     // xproj t-stride
#define NCLS    20
#define NB0     125      // L0 blocks: 1 wave, 4 units
#define NB1     250      // L1 blocks: 1 wave, 2 units
#define BIAS2   2.0f

typedef float v4f __attribute__((ext_vector_type(4)));

__device__ __forceinline__ float tanh_(float x){ return 2.0f/(1.0f+__expf(-2.0f*x)) - 1.0f; }
__device__ __forceinline__ v4f v4z() { v4f r; r.x=0.f; r.y=0.f; r.z=0.f; r.w=0.f; return r; }
__device__ __forceinline__ v4f v4sub(v4f v, float s){ v4f r; r.x=v.x-s; r.y=v.y-s; r.z=v.z-s; r.w=v.w-s; return r; }
__device__ __forceinline__ bool nz4(v4f v){ return v.x!=0.f && v.y!=0.f && v.z!=0.f && v.w!=0.f; }
__device__ __forceinline__ float dot4(v4f w, v4f x){ return w.x*x.x + w.y*x.y + w.z*x.z + w.w*x.w; }
__device__ __forceinline__ float sum4(v4f v){ return v.x+v.y+v.z+v.w; }

// keep these values materialized in VGPRs across the loop (defeat rematerialization)
#define PIN4(a,b,c,d) asm volatile("" : "+v"(a), "+v"(b), "+v"(c), "+v"(d))

// device-coherent poll loads (bypass L1/L2, served by LLC)
__device__ __forceinline__ void poll2(const float* p0, const float* p1, v4f& a, v4f& b) {
    asm volatile("global_load_dwordx4 %0, %2, off sc0 sc1\n\t"
                 "global_load_dwordx4 %1, %3, off sc0 sc1\n\t"
                 "s_waitcnt vmcnt(0)"
                 : "=&v"(a), "=&v"(b)
                 : "v"(p0), "v"(p1));
}
__device__ __forceinline__ void poll4(const float* p0, const float* p1,
                                      const float* p2, const float* p3,
                                      v4f& a, v4f& b, v4f& c, v4f& d) {
    asm volatile("global_load_dwordx4 %0, %4, off sc0 sc1\n\t"
                 "global_load_dwordx4 %1, %5, off sc0 sc1\n\t"
                 "global_load_dwordx4 %2, %6, off sc0 sc1\n\t"
                 "global_load_dwordx4 %3, %7, off sc0 sc1\n\t"
                 "s_waitcnt vmcnt(0)"
                 : "=&v"(a), "=&v"(b), "=&v"(c), "=&v"(d)
                 : "v"(p0), "v"(p1), "v"(p2), "v"(p3));
}
__device__ __forceinline__ void store1_cc(float* p, float v) {
    asm volatile("global_store_dword %0, %1, off sc0 sc1" :: "v"(p), "v"(v));
}

// h buffers t-indexed; 0 == not written (real values are h+2 in (1,3)).
__global__ __launch_bounds__(256) void lstm_init(float* hs) {
    int i = blockIdx.x*256 + threadIdx.x;
    const int NH4 = (T_STEPS+1)*HP/4;
    v4f b2; b2.x=BIAS2; b2.y=BIAS2; b2.z=BIAS2; b2.w=BIAS2;
    bool seed = (i < H/4) || (i >= NH4 && i < NH4 + H/4);
    ((v4f*)hs)[i] = seed ? b2 : v4z();
}

// xproj[row][t] = W_ih0[row,:] . emb[seq[t],:] + bih0[row] + bhh0[row]
__global__ __launch_bounds__(256) void xproj_kernel(
    const int* __restrict__ seq, const float* __restrict__ emb,
    const float* __restrict__ Wih0, const float* __restrict__ bih0,
    const float* __restrict__ bhh0, float* __restrict__ xp)
{
    __shared__ float xe[16][308];
    const int tid = threadIdx.x;
    const int t0 = blockIdx.x * 16;
    for (int i = tid; i < 16*76; i += 256) {
        int tt = i / 76, c4 = (i - tt*76) * 4;
        v4f val = v4z();
        if (c4 < E) val = *(const v4f*)&emb[(size_t)seq[t0+tt]*E + c4];
        *(v4f*)&xe[tt][c4] = val;
    }
    __syncthreads();
    const int rg = tid >> 4, tl = tid & 15;
    for (int k = 0; k < 125; ++k) {
        int row = k*16 + rg;
        const float* wr = Wih0 + (size_t)row*E;
        float acc = bih0[row] + bhh0[row];
        #pragma unroll 5
        for (int c = 0; c < 75; ++c)
            acc += dot4(*(const v4f*)(wr + 4*c), *(const v4f*)&xe[tl][4*c]);
        xp[(size_t)row*XPT + t0 + tl] = acc;
    }
}

// reduce-scatter 16 rows over 64 lanes -> lane L holds row 8b0+4b1+2b2+b3
__device__ __forceinline__ float reduce16(float* acc, int lane) {
    float v8[8];
    { const bool b = lane & 1;
      #pragma unroll
      for (int i = 0; i < 8; ++i) {
        float keep = b ? acc[8+i] : acc[i];
        float send = b ? acc[i]   : acc[8+i];
        v8[i] = keep + __shfl_xor(send, 1, 64); } }
    float v4a[4];
    { const bool b = lane & 2;
      #pragma unroll
      for (int i = 0; i < 4; ++i) {
        float keep = b ? v8[4+i] : v8[i];
        float send = b ? v8[i]   : v8[4+i];
        v4a[i] = keep + __shfl_xor(send, 2, 64); } }
    float v2a[2];
    { const bool b = lane & 4;
      #pragma unroll
      for (int i = 0; i < 2; ++i) {
        float keep = b ? v4a[2+i] : v4a[i];
        float send = b ? v4a[i]   : v4a[2+i];
        v2a[i] = keep + __shfl_xor(send, 4, 64); } }
    float v1;
    { const bool b = lane & 8;
      float keep = b ? v2a[1] : v2a[0];
      float send = b ? v2a[0] : v2a[1];
      v1 = keep + __shfl_xor(send, 8, 64); }
    v1 += __shfl_xor(v1, 16, 64);
    v1 += __shfl_xor(v1, 32, 64);
    return v1;
}

// reduce-scatter 8 rows over 64 lanes -> lane L holds row 4b0+2b1+b2
__device__ __forceinline__ float reduce8(float* acc, int lane) {
    float v4a[4];
    { const bool b = lane & 1;
      #pragma unroll
      for (int i = 0; i < 4; ++i) {
        float keep = b ? acc[4+i] : acc[i];
        float send = b ? acc[i]   : acc[4+i];
        v4a[i] = keep + __shfl_xor(send, 1, 64); } }
    float v2a[2];
    { const bool b = lane & 2;
      #pragma unroll
      for (int i = 0; i < 2; ++i) {
        float keep = b ? v4a[2+i] : v4a[i];
        float send = b ? v4a[i]   : v4a[2+i];
        v2a[i] = keep + __shfl_xor(send, 2, 64); } }
    float v1;
    { const bool b = lane & 4;
      float keep = b ? v2a[1] : v2a[0];
      float send = b ? v2a[0] : v2a[1];
      v1 = keep + __shfl_xor(send, 4, 64); }
    v1 += __shfl_xor(v1, 8, 64);
    v1 += __shfl_xor(v1, 16, 64);
    v1 += __shfl_xor(v1, 32, 64);
    return v1;
}

// L0 gates: lane's gate g = 2*b2+b3. xor4 -> g^2, xor8 -> g^1, xor12 -> g^3.
__device__ __forceinline__ float gates16(float x, int b2, int b3, float& cs) {
    const bool isG = (b2 == 1 && b3 == 0);
    float a = 1.f/(1.f + __expf(isG ? -2.f*x : -x));
    float act = isG ? 2.f*a - 1.f : a;
    float t1 = __shfl_xor(act, 4, 64);
    float t2 = __shfl_xor(act, 8, 64);
    float t3 = __shfl_xor(act, 12, 64);
    float gi = b2 ? (b3 ? t3 : t1) : (b3 ? t2 : act);
    float gf = b2 ? (b3 ? t1 : t3) : (b3 ? act : t2);
    float gg = b2 ? (b3 ? t2 : act) : (b3 ? t3 : t1);
    float go = b2 ? (b3 ? act : t2) : (b3 ? t1 : t3);
    cs = gf*cs + gi*gg;
    return go * tanh_(cs);
}

// L1 gates: lane's gate g = 2*b1+b2. xor2 -> g^2, xor4 -> g^1, xor6 -> g^3.
__device__ __forceinline__ float gates8(float x, int g, float& cs) {
    const bool isG = (g == 2);
    float a = 1.f/(1.f + __expf(isG ? -2.f*x : -x));
    float act = isG ? 2.f*a - 1.f : a;
    float t1 = __shfl_xor(act, 4, 64);   // g^1
    float t2 = __shfl_xor(act, 2, 64);   // g^2
    float t3 = __shfl_xor(act, 6, 64);   // g^3
    float gi = (g==0)?act:(g==1)?t1:(g==2)?t2:t3;
    float gf = (g==1)?act:(g==0)?t1:(g==3)?t2:t3;
    float gg = (g==2)?act:(g==3)?t1:(g==0)?t2:t3;
    float go = (g==3)?act:(g==2)?t1:(g==1)?t2:t3;
    cs = gf*cs + gi*gg;
    return go * tanh_(cs);
}

__launch_bounds__(64, 1)
__global__ void lstm_main(
    const float* __restrict__ Whh0,
    const float* __restrict__ Wih1, const float* __restrict__ Whh1,
    const float* __restrict__ bih1, const float* __restrict__ bhh1,
    const float* __restrict__ fcW, const float* __restrict__ fcb,
    float* __restrict__ out,
    const float* __restrict__ xp, float* h0s, float* h1s)
{
    const int blk  = blockIdx.x;
    const int j    = (int)(threadIdx.x & 63);
    const int b0 = j&1, b1=(j>>1)&1, b2=(j>>2)&1, b3=(j>>3)&1;
    const int cA = 4*j, cB = 256 + 4*j;          // interleaved coalesced chunks
    const bool hasB = (cB + 4 <= H);             // j <= 60

    if (blk < NB0) {
        // ================= layer 0: 1 wave, 4 units, 16 rows =================
        const int u0 = 4*blk;
        const int unit = 2*b0 + b1, gate = 2*b2 + b3;
        v4f w0[16], w1[16];
        float rs[16];
        #pragma unroll
        for (int r = 0; r < 16; ++r) {
            const int R_ = (r&3)*H + u0 + (r>>2);
            const float* wh = Whh0 + (size_t)R_*H;
            w0[r] = *(const v4f*)(wh + cA);
            w1[r] = hasB ? *(const v4f*)(wh + cB) : v4z();
            rs[r] = sum4(w0[r]) + sum4(w1[r]);
        }
        const float off = -BIAS2 * reduce16(rs, j);          // folds h+2 encoding
        const float* xpp = xp + (size_t)(gate*H + u0 + unit)*XPT;
        float cs = 0.f;

        for (int t = 1; t <= T_STEPS; ++t) {
            PIN4(w0[0],w0[1],w0[2],w0[3]);   PIN4(w0[4],w0[5],w0[6],w0[7]);
            PIN4(w0[8],w0[9],w0[10],w0[11]); PIN4(w0[12],w0[13],w0[14],w0[15]);
            PIN4(w1[0],w1[1],w1[2],w1[3]);   PIN4(w1[4],w1[5],w1[6],w1[7]);
            PIN4(w1[8],w1[9],w1[10],w1[11]); PIN4(w1[12],w1[13],w1[14],w1[15]);
            float xpv = xpp[t-1];
            const float* hp = h0s + (size_t)(t-1)*HP;
            v4f A, B; bool ok = false;
            while (!__all(ok)) {
                if (!ok) {
                    poll2(hp + cA, hp + cB, A, B);
                    ok = nz4(A) && (!hasB || nz4(B));
                }
            }
            float acc[16];
            #pragma unroll
            for (int r = 0; r < 16; ++r)
                acc[r] = dot4(w0[r], A) + dot4(w1[r], B);    // w1=0 masks pad
            float v = reduce16(acc, j);
            float hval = gates16(v + xpv + off, b2, b3, cs);
            if ((j & 60) == 0)
                store1_cc(h0s + (size_t)t*HP + u0 + unit, hval + BIAS2);
        }
    } else {
        // ================= layer 1: 1 wave, 2 units, 8 rows =================
        const int g1 = blk - NB0;
        const int u0 = 2*g1;
        const int unit = b0, gate = 2*b1 + b2;
        v4f wa[8], wb[8], wc[8], wd[8];
        float rs[8];
        #pragma unroll
        for (int r = 0; r < 8; ++r) {
            const int R_ = (r&3)*H + u0 + (r>>2);
            const float* wi = Wih1 + (size_t)R_*H;
            const float* wh = Whh1 + (size_t)R_*H;
            wa[r] = *(const v4f*)(wi + cA);
            wb[r] = hasB ? *(const v4f*)(wi + cB) : v4z();
            wc[r] = *(const v4f*)(wh + cA);
            wd[r] = hasB ? *(const v4f*)(wh + cB) : v4z();
            rs[r] = sum4(wa[r]) + sum4(wb[r]) + sum4(wc[r]) + sum4(wd[r]);
        }
        float off;
        {
            const int R_my = gate*H + u0 + unit;
            off = bih1[R_my] + bhh1[R_my] - BIAS2 * reduce8(rs, j);
        }
        float cs = 0.f;

        for (int t = 1; t <= T_STEPS; ++t) {
            PIN4(wa[0],wa[1],wa[2],wa[3]); PIN4(wa[4],wa[5],wa[6],wa[7]);
            PIN4(wb[0],wb[1],wb[2],wb[3]); PIN4(wb[4],wb[5],wb[6],wb[7]);
            PIN4(wc[0],wc[1],wc[2],wc[3]); PIN4(wc[4],wc[5],wc[6],wc[7]);
            PIN4(wd[0],wd[1],wd[2],wd[3]); PIN4(wd[4],wd[5],wd[6],wd[7]);
            const float* pa = h0s + (size_t)t*HP;        // h0(t)
            const float* pb = h1s + (size_t)(t-1)*HP;    // h1(t-1)
            v4f A, B, C, D; bool ok = false;
            while (!__all(ok)) {
                if (!ok) {
                    poll4(pa + cA, pa + cB, pb + cA, pb + cB, A, B, C, D);
                    ok = nz4(A) && nz4(C) && (!hasB || (nz4(B) && nz4(D)));
                }
            }
            float acc[8];
            #pragma unroll
            for (int r = 0; r < 8; ++r)
                acc[r] = dot4(wa[r], A) + dot4(wb[r], B)
                       + dot4(wc[r], C) + dot4(wd[r], D);
            float v = reduce8(acc, j);
            float hval = gates8(v + off, gate, cs);
            if ((j & 62) == 0)
                store1_cc(h1s + (size_t)t*HP + u0 + unit, hval + BIAS2);
        }

        if (g1 == 0) {
            // final FC on h1[T]
            const float* hT = h1s + (size_t)T_STEPS*HP;
            v4f A, B; bool ok = false;
            while (!__all(ok)) {
                if (!ok) {
                    poll2(hT + cA, hT + cB, A, B);
                    ok = nz4(A) && (!hasB || nz4(B));
                }
            }
            v4f v0 = v4sub(A, BIAS2);
            v4f v1 = hasB ? v4sub(B, BIAS2) : v4z();
            #pragma unroll 4
            for (int r = 0; r < NCLS; ++r) {
                const float* wr = fcW + (size_t)r*H;
                v4f fa = *(const v4f*)(wr + cA);
                v4f fb = hasB ? *(const v4f*)(wr + cB) : v4z();
                float a = dot4(fa, v0) + dot4(fb, v1);
                #pragma unroll
                for (int m = 32; m >= 1; m >>= 1) a += __shfl_xor(a, m, 64);
                if (j == 0) out[r] = a + fcb[r];
            }
        }
    }
}

extern "C" void kernel_launch(void* const* d_in, const int* in_sizes, int n_in,
                              void* d_out, int out_size, void* d_ws, size_t ws_size,
                              hipStream_t stream)
{
    const int*   seq  = (const int*)d_in[0];
    const float* emb  = (const float*)d_in[1];
    const float* Wih0 = (const float*)d_in[2];
    const float* Whh0 = (const float*)d_in[3];
    const float* bih0 = (const float*)d_in[4];
    const float* bhh0 = (const float*)d_in[5];
    const float* Wih1 = (const float*)d_in[6];
    const float* Whh1 = (const float*)d_in[7];
    const float* bih1 = (const float*)d_in[8];
    const float* bhh1 = (const float*)d_in[9];
    const float* fcW  = (const float*)d_in[10];
    const float* fcb  = (const float*)d_in[11];
    float* out = (float*)d_out;

    float* h0s = (float*)d_ws;
    float* h1s = h0s + (size_t)(T_STEPS+1)*HP;
    float* xpj = h1s + (size_t)(T_STEPS+1)*HP;   // 2000 rows x 2048 floats

    hipLaunchKernelGGL(lstm_init, dim3(2049), dim3(256), 0, stream, h0s);
    hipLaunchKernelGGL(xproj_kernel, dim3(T_STEPS/16), dim3(256), 0, stream,
                       seq, emb, Wih0, bih0, bhh0, xpj);
    hipLaunchKernelGGL(lstm_main, dim3(NB0 + NB1), dim3(64), 0, stream,
                       Whh0, Wih1, Whh1, bih1, bhh1, fcW, fcb, out, xpj, h0s, h1s);
}

// Round 7
// 7646.922 us; speedup vs baseline: 1.0047x; 1.0047x over previous
//
#include <hip/hip_runtime.h>

#define T_STEPS 2048
#define H       500
#define E       300
#define HP      512      // padded h stride (floats)
#define XPT     2048     // xproj t-stride
#define NCLS    20
#define NB0     125      // L0 blocks: 1 wave, 4 units
#define NB1     250      // L1 blocks: 1 wave, 2 units
#define BIAS2   2.0f

typedef float v4f __attribute__((ext_vector_type(4)));

__device__ __forceinline__ float tanh_(float x){ return 2.0f/(1.0f+__expf(-2.0f*x)) - 1.0f; }
__device__ __forceinline__ v4f v4z() { v4f r; r.x=0.f; r.y=0.f; r.z=0.f; r.w=0.f; return r; }
__device__ __forceinline__ v4f v4sub(v4f v, float s){ v4f r; r.x=v.x-s; r.y=v.y-s; r.z=v.z-s; r.w=v.w-s; return r; }
__device__ __forceinline__ bool nz4(v4f v){ return v.x!=0.f && v.y!=0.f && v.z!=0.f && v.w!=0.f; }
__device__ __forceinline__ float dot4(v4f w, v4f x){ return w.x*x.x + w.y*x.y + w.z*x.z + w.w*x.w; }
__device__ __forceinline__ float sum4(v4f v){ return v.x+v.y+v.z+v.w; }

// one-time value laundering: value becomes asm output -> compiler cannot
// rematerialize it from memory inside the loop; must keep it live (VGPR).
#define PIN4(a,b,c,d) asm volatile("" : "+v"(a), "+v"(b), "+v"(c), "+v"(d))

// device-coherent poll loads (bypass L1/L2, served by LLC)
__device__ __forceinline__ void poll2(const float* p0, const float* p1, v4f& a, v4f& b) {
    asm volatile("global_load_dwordx4 %0, %2, off sc0 sc1\n\t"
                 "global_load_dwordx4 %1, %3, off sc0 sc1\n\t"
                 "s_waitcnt vmcnt(0)"
                 : "=&v"(a), "=&v"(b)
                 : "v"(p0), "v"(p1));
}
__device__ __forceinline__ void poll4(const float* p0, const float* p1,
                                      const float* p2, const float* p3,
                                      v4f& a, v4f& b, v4f& c, v4f& d) {
    asm volatile("global_load_dwordx4 %0, %4, off sc0 sc1\n\t"
                 "global_load_dwordx4 %1, %5, off sc0 sc1\n\t"
                 "global_load_dwordx4 %2, %6, off sc0 sc1\n\t"
                 "global_load_dwordx4 %3, %7, off sc0 sc1\n\t"
                 "s_waitcnt vmcnt(0)"
                 : "=&v"(a), "=&v"(b), "=&v"(c), "=&v"(d)
                 : "v"(p0), "v"(p1), "v"(p2), "v"(p3));
}
__device__ __forceinline__ void store1_cc(float* p, float v) {
    asm volatile("global_store_dword %0, %1, off sc0 sc1" :: "v"(p), "v"(v));
}

// h buffers t-indexed; 0 == not written (real values are h+2 in (1,3)).
__global__ __launch_bounds__(256) void lstm_init(float* hs) {
    int i = blockIdx.x*256 + threadIdx.x;
    const int NH4 = (T_STEPS+1)*HP/4;
    v4f b2; b2.x=BIAS2; b2.y=BIAS2; b2.z=BIAS2; b2.w=BIAS2;
    bool seed = (i < H/4) || (i >= NH4 && i < NH4 + H/4);
    ((v4f*)hs)[i] = seed ? b2 : v4z();
}

// xproj[row][t] = W_ih0[row,:] . emb[seq[t],:] + bih0[row] + bhh0[row]
__global__ __launch_bounds__(256) void xproj_kernel(
    const int* __restrict__ seq, const float* __restrict__ emb,
    const float* __restrict__ Wih0, const float* __restrict__ bih0,
    const float* __restrict__ bhh0, float* __restrict__ xp)
{
    __shared__ float xe[16][308];
    const int tid = threadIdx.x;
    const int t0 = blockIdx.x * 16;
    for (int i = tid; i < 16*76; i += 256) {
        int tt = i / 76, c4 = (i - tt*76) * 4;
        v4f val = v4z();
        if (c4 < E) val = *(const v4f*)&emb[(size_t)seq[t0+tt]*E + c4];
        *(v4f*)&xe[tt][c4] = val;
    }
    __syncthreads();
    const int rg = tid >> 4, tl = tid & 15;
    for (int k = 0; k < 125; ++k) {
        int row = k*16 + rg;
        const float* wr = Wih0 + (size_t)row*E;
        float acc = bih0[row] + bhh0[row];
        #pragma unroll 5
        for (int c = 0; c < 75; ++c)
            acc += dot4(*(const v4f*)(wr + 4*c), *(const v4f*)&xe[tl][4*c]);
        xp[(size_t)row*XPT + t0 + tl] = acc;
    }
}

// reduce-scatter 16 rows over 64 lanes -> lane L holds row 8b0+4b1+2b2+b3
__device__ __forceinline__ float reduce16(float* acc, int lane) {
    float v8[8];
    { const bool b = lane & 1;
      #pragma unroll
      for (int i = 0; i < 8; ++i) {
        float keep = b ? acc[8+i] : acc[i];
        float send = b ? acc[i]   : acc[8+i];
        v8[i] = keep + __shfl_xor(send, 1, 64); } }
    float v4a[4];
    { const bool b = lane & 2;
      #pragma unroll
      for (int i = 0; i < 4; ++i) {
        float keep = b ? v8[4+i] : v8[i];
        float send = b ? v8[i]   : v8[4+i];
        v4a[i] = keep + __shfl_xor(send, 2, 64); } }
    float v2a[2];
    { const bool b = lane & 4;
      #pragma unroll
      for (int i = 0; i < 2; ++i) {
        float keep = b ? v4a[2+i] : v4a[i];
        float send = b ? v4a[i]   : v4a[2+i];
        v2a[i] = keep + __shfl_xor(send, 4, 64); } }
    float v1;
    { const bool b = lane & 8;
      float keep = b ? v2a[1] : v2a[0];
      float send = b ? v2a[0] : v2a[1];
      v1 = keep + __shfl_xor(send, 8, 64); }
    v1 += __shfl_xor(v1, 16, 64);
    v1 += __shfl_xor(v1, 32, 64);
    return v1;
}

// reduce-scatter 8 rows over 64 lanes -> lane L holds row 4b0+2b1+b2
__device__ __forceinline__ float reduce8(float* acc, int lane) {
    float v4a[4];
    { const bool b = lane & 1;
      #pragma unroll
      for (int i = 0; i < 4; ++i) {
        float keep = b ? acc[4+i] : acc[i];
        float send = b ? acc[i]   : acc[4+i];
        v4a[i] = keep + __shfl_xor(send, 1, 64); } }
    float v2a[2];
    { const bool b = lane & 2;
      #pragma unroll
      for (int i = 0; i < 2; ++i) {
        float keep = b ? v4a[2+i] : v4a[i];
        float send = b ? v4a[i]   : v4a[2+i];
        v2a[i] = keep + __shfl_xor(send, 2, 64); } }
    float v1;
    { const bool b = lane & 4;
      float keep = b ? v2a[1] : v2a[0];
      float send = b ? v2a[0] : v2a[1];
      v1 = keep + __shfl_xor(send, 4, 64); }
    v1 += __shfl_xor(v1, 8, 64);
    v1 += __shfl_xor(v1, 16, 64);
    v1 += __shfl_xor(v1, 32, 64);
    return v1;
}

// L0 gates: lane's gate g = 2*b2+b3. xor4 -> g^2, xor8 -> g^1, xor12 -> g^3.
__device__ __forceinline__ float gates16(float x, int b2, int b3, float& cs) {
    const bool isG = (b2 == 1 && b3 == 0);
    float a = 1.f/(1.f + __expf(isG ? -2.f*x : -x));
    float act = isG ? 2.f*a - 1.f : a;
    float t1 = __shfl_xor(act, 4, 64);
    float t2 = __shfl_xor(act, 8, 64);
    float t3 = __shfl_xor(act, 12, 64);
    float gi = b2 ? (b3 ? t3 : t1) : (b3 ? t2 : act);
    float gf = b2 ? (b3 ? t1 : t3) : (b3 ? act : t2);
    float gg = b2 ? (b3 ? t2 : act) : (b3 ? t3 : t1);
    float go = b2 ? (b3 ? act : t2) : (b3 ? t1 : t3);
    cs = gf*cs + gi*gg;
    return go * tanh_(cs);
}

// L1 gates: lane's gate g = 2*b1+b2. xor2 -> g^2, xor4 -> g^1, xor6 -> g^3.
__device__ __forceinline__ float gates8(float x, int g, float& cs) {
    const bool isG = (g == 2);
    float a = 1.f/(1.f + __expf(isG ? -2.f*x : -x));
    float act = isG ? 2.f*a - 1.f : a;
    float t1 = __shfl_xor(act, 4, 64);   // g^1
    float t2 = __shfl_xor(act, 2, 64);   // g^2
    float t3 = __shfl_xor(act, 6, 64);   // g^3
    float gi = (g==0)?act:(g==1)?t1:(g==2)?t2:t3;
    float gf = (g==1)?act:(g==0)?t1:(g==3)?t2:t3;
    float gg = (g==2)?act:(g==3)?t1:(g==0)?t2:t3;
    float go = (g==3)?act:(g==2)?t1:(g==1)?t2:t3;
    cs = gf*cs + gi*gg;
    return go * tanh_(cs);
}

__launch_bounds__(64, 1)
__global__ void lstm_main(
    const float* __restrict__ Whh0,
    const float* __restrict__ Wih1, const float* __restrict__ Whh1,
    const float* __restrict__ bih1, const float* __restrict__ bhh1,
    const float* __restrict__ fcW, const float* __restrict__ fcb,
    float* __restrict__ out,
    const float* __restrict__ xp, float* h0s, float* h1s)
{
    const int blk  = blockIdx.x;
    const int j    = (int)(threadIdx.x & 63);
    const int b0 = j&1, b1=(j>>1)&1, b2=(j>>2)&1, b3=(j>>3)&1;
    const int cA = 4*j, cB = 256 + 4*j;          // interleaved coalesced chunks
    const bool hasB = (cB + 4 <= H);             // j <= 60

    if (blk < NB0) {
        // ================= layer 0: 1 wave, 4 units, 16 rows =================
        const int u0 = 4*blk;
        const int unit = 2*b0 + b1, gate = 2*b2 + b3;
        v4f w0[16], w1[16];
        float rs[16];
        #pragma unroll
        for (int r = 0; r < 16; ++r) {
            const int R_ = (r&3)*H + u0 + (r>>2);
            const float* wh = Whh0 + (size_t)R_*H;
            w0[r] = *(const v4f*)(wh + cA);
            w1[r] = hasB ? *(const v4f*)(wh + cB) : v4z();
        }
        // pin ONCE: values become asm outputs -> non-rematerializable in loop
        PIN4(w0[0],w0[1],w0[2],w0[3]);   PIN4(w0[4],w0[5],w0[6],w0[7]);
        PIN4(w0[8],w0[9],w0[10],w0[11]); PIN4(w0[12],w0[13],w0[14],w0[15]);
        PIN4(w1[0],w1[1],w1[2],w1[3]);   PIN4(w1[4],w1[5],w1[6],w1[7]);
        PIN4(w1[8],w1[9],w1[10],w1[11]); PIN4(w1[12],w1[13],w1[14],w1[15]);
        #pragma unroll
        for (int r = 0; r < 16; ++r) rs[r] = sum4(w0[r]) + sum4(w1[r]);
        const float off = -BIAS2 * reduce16(rs, j);          // folds h+2 encoding
        const float* xpp = xp + (size_t)(gate*H + u0 + unit)*XPT;
        float cs = 0.f;

        for (int t = 1; t <= T_STEPS; ++t) {
            float xpv = xpp[t-1];
            const float* hp = h0s + (size_t)(t-1)*HP;
            v4f A, B; bool ok = false;
            while (!__all(ok)) {
                if (!ok) {
                    poll2(hp + cA, hp + cB, A, B);
                    ok = nz4(A) && (!hasB || nz4(B));
                }
            }
            float acc[16];
            #pragma unroll
            for (int r = 0; r < 16; ++r)
                acc[r] = dot4(w0[r], A) + dot4(w1[r], B);    // w1=0 masks pad
            float v = reduce16(acc, j);
            float hval = gates16(v + xpv + off, b2, b3, cs);
            if ((j & 60) == 0)
                store1_cc(h0s + (size_t)t*HP + u0 + unit, hval + BIAS2);
        }
    } else {
        // ================= layer 1: 1 wave, 2 units, 8 rows =================
        const int g1 = blk - NB0;
        const int u0 = 2*g1;
        const int unit = b0, gate = 2*b1 + b2;
        v4f wa[8], wb[8], wc[8], wd[8];
        float rs[8];
        #pragma unroll
        for (int r = 0; r < 8; ++r) {
            const int R_ = (r&3)*H + u0 + (r>>2);
            const float* wi = Wih1 + (size_t)R_*H;
            const float* wh = Whh1 + (size_t)R_*H;
            wa[r] = *(const v4f*)(wi + cA);
            wb[r] = hasB ? *(const v4f*)(wi + cB) : v4z();
            wc[r] = *(const v4f*)(wh + cA);
            wd[r] = hasB ? *(const v4f*)(wh + cB) : v4z();
        }
        PIN4(wa[0],wa[1],wa[2],wa[3]); PIN4(wa[4],wa[5],wa[6],wa[7]);
        PIN4(wb[0],wb[1],wb[2],wb[3]); PIN4(wb[4],wb[5],wb[6],wb[7]);
        PIN4(wc[0],wc[1],wc[2],wc[3]); PIN4(wc[4],wc[5],wc[6],wc[7]);
        PIN4(wd[0],wd[1],wd[2],wd[3]); PIN4(wd[4],wd[5],wd[6],wd[7]);
        #pragma unroll
        for (int r = 0; r < 8; ++r)
            rs[r] = sum4(wa[r]) + sum4(wb[r]) + sum4(wc[r]) + sum4(wd[r]);
        float off;
        {
            const int R_my = gate*H + u0 + unit;
            off = bih1[R_my] + bhh1[R_my] - BIAS2 * reduce8(rs, j);
        }
        float cs = 0.f;

        for (int t = 1; t <= T_STEPS; ++t) {
            const float* pa = h0s + (size_t)t*HP;        // h0(t)
            const float* pb = h1s + (size_t)(t-1)*HP;    // h1(t-1)
            v4f A, B, C, D; bool ok = false;
            while (!__all(ok)) {
                if (!ok) {
                    poll4(pa + cA, pa + cB, pb + cA, pb + cB, A, B, C, D);
                    ok = nz4(A) && nz4(C) && (!hasB || (nz4(B) && nz4(D)));
                }
            }
            float acc[8];
            #pragma unroll
            for (int r = 0; r < 8; ++r)
                acc[r] = dot4(wa[r], A) + dot4(wb[r], B)
                       + dot4(wc[r], C) + dot4(wd[r], D);
            float v = reduce8(acc, j);
            float hval = gates8(v + off, gate, cs);
            if ((j & 62) == 0)
                store1_cc(h1s + (size_t)t*HP + u0 + unit, hval + BIAS2);
        }

        if (g1 == 0) {
            // final FC on h1[T]
            const float* hT = h1s + (size_t)T_STEPS*HP;
            v4f A, B; bool ok = false;
            while (!__all(ok)) {
                if (!ok) {
                    poll2(hT + cA, hT + cB, A, B);
                    ok = nz4(A) && (!hasB || nz4(B));
                }
            }
            v4f v0 = v4sub(A, BIAS2);
            v4f v1 = hasB ? v4sub(B, BIAS2) : v4z();
            #pragma unroll 4
            for (int r = 0; r < NCLS; ++r) {
                const float* wr = fcW + (size_t)r*H;
                v4f fa = *(const v4f*)(wr + cA);
                v4f fb = hasB ? *(const v4f*)(wr + cB) : v4z();
                float a = dot4(fa, v0) + dot4(fb, v1);
                #pragma unroll
                for (int m = 32; m >= 1; m >>= 1) a += __shfl_xor(a, m, 64);
                if (j == 0) out[r] = a + fcb[r];
            }
        }
    }
}

extern "C" void kernel_launch(void* const* d_in, const int* in_sizes, int n_in,
                              void* d_out, int out_size, void* d_ws, size_t ws_size,
                              hipStream_t stream)
{
    const int*   seq  = (const int*)d_in[0];
    const float* emb  = (const float*)d_in[1];
    const float* Wih0 = (const float*)d_in[2];
    const float* Whh0 = (const float*)d_in[3];
    const float* bih0 = (const float*)d_in[4];
    const float* bhh0 = (const float*)d_in[5];
    const float* Wih1 = (const float*)d_in[6];
    const float* Whh1 = (const float*)d_in[7];
    const float* bih1 = (const float*)d_in[8];
    const float* bhh1 = (const float*)d_in[9];
    const float* fcW  = (const float*)d_in[10];
    const float* fcb  = (const float*)d_in[11];
    float* out = (float*)d_out;

    float* h0s = (float*)d_ws;
    float* h1s = h0s + (size_t)(T_STEPS+1)*HP;
    float* xpj = h1s + (size_t)(T_STEPS+1)*HP;   // 2000 rows x 2048 floats

    hipLaunchKernelGGL(lstm_init, dim3(2049), dim3(256), 0, stream, h0s);
    hipLaunchKernelGGL(xproj_kernel, dim3(T_STEPS/16), dim3(256), 0, stream,
                       seq, emb, Wih0, bih0, bhh0, xpj);
    hipLaunchKernelGGL(lstm_main, dim3(NB0 + NB1), dim3(64), 0, stream,
                       Whh0, Wih1, Whh1, bih1, bhh1, fcW, fcb, out, xpj, h0s, h1s);
}

// Round 10
// 5149.769 us; speedup vs baseline: 1.4919x; 1.4849x over previous
//
#include <hip/hip_runtime.h>

#define T_STEPS 2048
#define H       500
#define E       300
#define HP      512
#define NCLS    20
#define NB0     125          // L0 blocks (4 waves, 4 units each)
#define NB1     125          // L1 blocks (4 waves, 4 units each)
#define NREP    4            // slot replicas
#define K0      8            // h0 rotating slots (sign period 16)
#define K1      4            // h1 rotating slots (sign period 8)  [R8 deadlock fix: was 2]
#define THR_LAG 4            // L0 throttle: require h1(t-4)

typedef float v2f __attribute__((ext_vector_type(2)));
typedef float v4f __attribute__((ext_vector_type(4)));

__device__ __forceinline__ float tanh_(float x){ return 2.0f/(1.0f+__expf(-2.0f*x)) - 1.0f; }
__device__ __forceinline__ v2f v2z(){ v2f r; r.x=0.f; r.y=0.f; return r; }
__device__ __forceinline__ v4f v4z(){ v4f r; r.x=0.f; r.y=0.f; r.z=0.f; r.w=0.f; return r; }
__device__ __forceinline__ float dot4(v4f w, v4f x){ return w.x*x.x + w.y*x.y + w.z*x.z + w.w*x.w; }

// sign tags: h0 flips every K0=8 steps, h1 every K1=4 steps
__device__ __forceinline__ float s0f(int t){ return ((t>>3)&1) ? -1.f : 1.f; }
__device__ __forceinline__ float s1f(int t){ return ((t>>2)&1) ? -1.f : 1.f; }

__device__ __forceinline__ bool valid2(v2f v, float s){
    return (s > 0.f) ? (v.x > 0.5f && v.y > 0.5f) : (v.x < -0.5f && v.y < -0.5f);
}
__device__ __forceinline__ bool valid4(v4f v, float s){
    return (s > 0.f) ? (v.x > 0.5f && v.y > 0.5f && v.z > 0.5f && v.w > 0.5f)
                     : (v.x < -0.5f && v.y < -0.5f && v.z < -0.5f && v.w < -0.5f);
}

// device-coherent polls (LLC-served; slots are hot lines)
__device__ __forceinline__ void pollx2_2(const float* p0, const float* p1, v2f& a, v2f& b){
    asm volatile("global_load_dwordx2 %0, %2, off sc0 sc1\n\t"
                 "global_load_dwordx2 %1, %3, off sc0 sc1\n\t"
                 "s_waitcnt vmcnt(0)"
                 : "=&v"(a), "=&v"(b) : "v"(p0), "v"(p1));
}
__device__ __forceinline__ v4f pollx4(const float* p){
    v4f a;
    asm volatile("global_load_dwordx4 %0, %1, off sc0 sc1\n\ts_waitcnt vmcnt(0)"
                 : "=&v"(a) : "v"(p));
    return a;
}
__device__ __forceinline__ void pollx4_2(const float* p0, const float* p1, v4f& a, v4f& b){
    asm volatile("global_load_dwordx4 %0, %2, off sc0 sc1\n\t"
                 "global_load_dwordx4 %1, %3, off sc0 sc1\n\t"
                 "s_waitcnt vmcnt(0)"
                 : "=&v"(a), "=&v"(b) : "v"(p0), "v"(p1));
}
__device__ __forceinline__ void store1_cc(float* p, float v){
    asm volatile("global_store_dword %0, %1, off sc0 sc1" :: "v"(p), "v"(v));
}

// h0rep[NREP][K0][HP], h1rep[NREP][K1][HP]; slot0 seeded with (0+2)*+1 = 2.0
__global__ __launch_bounds__(256) void lstm_init(float* h0rep, float* h1rep){
    int i = blockIdx.x*256 + threadIdx.x;
    if (i < NREP*K0*HP) {
        int rem = i % (K0*HP), slot = rem / HP, col = rem % HP;
        h0rep[i] = (slot == 0 && col < H) ? 2.0f : 0.f;
    }
    int i1 = i - NREP*K0*HP;
    if (i1 >= 0 && i1 < NREP*K1*HP) {
        int rem = i1 % (K1*HP), slot = rem / HP, col = rem % HP;
        h1rep[i1] = (slot == 0 && col < H) ? 2.0f : 0.f;
    }
}

// reduce-scatter 16 rows over 64 lanes -> lane L holds row 8b0+4b1+2b2+b3
__device__ __forceinline__ float reduce16(float* acc, int lane){
    float v8[8];
    { const bool b = lane & 1;
      #pragma unroll
      for (int i = 0; i < 8; ++i){
        float keep = b ? acc[8+i] : acc[i];
        float send = b ? acc[i]   : acc[8+i];
        v8[i] = keep + __shfl_xor(send, 1, 64); } }
    float v4a[4];
    { const bool b = lane & 2;
      #pragma unroll
      for (int i = 0; i < 4; ++i){
        float keep = b ? v8[4+i] : v8[i];
        float send = b ? v8[i]   : v8[4+i];
        v4a[i] = keep + __shfl_xor(send, 2, 64); } }
    float v2a[2];
    { const bool b = lane & 4;
      #pragma unroll
      for (int i = 0; i < 2; ++i){
        float keep = b ? v4a[2+i] : v4a[i];
        float send = b ? v4a[i]   : v4a[2+i];
        v2a[i] = keep + __shfl_xor(send, 4, 64); } }
    float v1;
    { const bool b = lane & 8;
      float keep = b ? v2a[1] : v2a[0];
      float send = b ? v2a[0] : v2a[1];
      v1 = keep + __shfl_xor(send, 8, 64); }
    v1 += __shfl_xor(v1, 16, 64);
    v1 += __shfl_xor(v1, 32, 64);
    return v1;
}

// lane's gate g = 2*b2+b3; xor4 flips b2 (g^2), xor8 flips b3 (g^1), xor12 both
__device__ __forceinline__ float gates16(float x, int b2, int b3, float& cs){
    const bool isG = (b2 == 1 && b3 == 0);   // gate==2 (tanh)
    float a = 1.f/(1.f + __expf(isG ? -2.f*x : -x));
    float act = isG ? 2.f*a - 1.f : a;
    float t1 = __shfl_xor(act, 4, 64);
    float t2 = __shfl_xor(act, 8, 64);
    float t3 = __shfl_xor(act, 12, 64);
    float gi = b2 ? (b3 ? t3 : t1) : (b3 ? t2 : act);
    float gf = b2 ? (b3 ? t1 : t3) : (b3 ? act : t2);
    float gg = b2 ? (b3 ? t2 : act) : (b3 ? t3 : t1);
    float go = b2 ? (b3 ? act : t2) : (b3 ? t1 : t3);
    cs = gf*cs + gi*gg;
    return go * tanh_(cs);
}

__launch_bounds__(256, 1)
__global__ void lstm_main(
    const int* __restrict__ seq, const float* __restrict__ emb,
    const float* __restrict__ Wih0, const float* __restrict__ Whh0,
    const float* __restrict__ bih0, const float* __restrict__ bhh0,
    const float* __restrict__ Wih1, const float* __restrict__ Whh1,
    const float* __restrict__ bih1, const float* __restrict__ bhh1,
    const float* __restrict__ fcW, const float* __restrict__ fcb,
    float* __restrict__ out,
    float* h0rep, float* h1rep)
{
    __shared__ float part[2][3][16];

    const int blk = blockIdx.x;
    const int wid = (int)(threadIdx.x >> 6);
    const int j   = (int)(threadIdx.x & 63);
    const int b0 = j&1, b1=(j>>1)&1, b2=(j>>2)&1, b3=(j>>3)&1;
    const int unit = 2*b0 + b1;          // lane's row: r = 8b0+4b1+2b2+b3
    const int gate = 2*b2 + b3;
    const int rep  = (blk + wid) & (NREP-1);

    if (blk < NB0) {
        // ======================= layer 0 =======================
        const int u0 = 4*blk;
        const int cw = 128*wid + 2*j;                 // this lane's 2 cols
        const bool hAct = (cw < H);
        const bool xAct = (cw < E);

        // recurrent weights (2 cols x 16 rows = 32 VGPR) — resident
        v2f w2[16];
        #pragma unroll
        for (int r = 0; r < 16; ++r) {
            const int R_ = (r&3)*H + u0 + (r>>2);
            w2[r] = hAct ? *(const v2f*)(Whh0 + (size_t)R_*H + cw) : v2z();
        }
        float bs = 0.f;
        if (wid == 0) { const int R_my = gate*H + u0 + unit; bs = bih0[R_my] + bhh0[R_my]; }

        float cs = 0.f;
        v2f xcur = xAct ? *(const v2f*)(emb + (size_t)seq[0]*E + cw) : v2z();

        float* h0base = h0rep + (size_t)rep*K0*HP;
        float* h1base = h1rep + (size_t)rep*K1*HP;

        for (int t = 1; t <= T_STEPS; ++t) {
            // prefetch next x (consumed next iteration; latency hidden)
            v2f xn = v2z();
            if (xAct && t < T_STEPS) xn = *(const v2f*)(emb + (size_t)seq[t]*E + cw);

            // x-projection partials (L1$-resident Wih0 slice; pre-poll)
            float acc[16];
            #pragma unroll
            for (int r = 0; r < 16; ++r) {
                const int R_ = (r&3)*H + u0 + (r>>2);
                v2f wi = xAct ? *(const v2f*)(Wih0 + (size_t)R_*E + cw) : v2z();
                acc[r] = wi.x*xcur.x + wi.y*xcur.y;
            }

            // rendezvous: h0(t-1) + throttle h1(max(t-4,0))
            const float sM = s0f(t-1);
            const int tau = (t > THR_LAG) ? t - THR_LAG : 0;
            const float sT = s1f(tau);
            const float* pm = h0base + (size_t)((t-1)&(K0-1))*HP + cw;
            const float* pt = h1base + (size_t)(tau&(K1-1))*HP + cw;
            v2f Mv = v2z(); bool gm = !hAct, gt = !hAct;
            while (!__all(gm && gt)) {
                if (!(gm && gt)) {
                    v2f m, th;
                    pollx2_2(pm, pt, m, th);
                    if (!gm && valid2(m, sM)) { Mv = m; gm = true; }
                    if (!gt && valid2(th, sT)) gt = true;
                }
            }

            // decode h = v*s - 2, recurrent dots
            v2f hd; hd.x = __builtin_fmaf(Mv.x, sM, -2.f); hd.y = __builtin_fmaf(Mv.y, sM, -2.f);
            #pragma unroll
            for (int r = 0; r < 16; ++r)
                acc[r] += w2[r].x*hd.x + w2[r].y*hd.y;

            float red = reduce16(acc, j);

            if (wid != 0) { if (j < 16) part[t&1][wid-1][j] = red; }
            __syncthreads();
            if (wid == 0) {
                float val = red + part[t&1][0][j&15] + part[t&1][1][j&15] + part[t&1][2][j&15] + bs;
                float hval = gates16(val, b2, b3, cs);
                if ((j & 60) == 0) {
                    const float sv = s0f(t);
                    const float outv = (hval + 2.f) * sv;
                    const size_t off = (size_t)(t&(K0-1))*HP + u0 + unit;
                    #pragma unroll
                    for (int rr = 0; rr < NREP; ++rr)
                        store1_cc(h0rep + (size_t)rr*K0*HP + off, outv);
                }
            }
            xcur = xn;
        }
    } else {
        // ======================= layer 1 =======================
        const int g  = blk - NB0;
        const int u0 = 4*g;
        const int c4 = ((wid&1) ? 256 : 0) + 4*j;     // cols of my stream chunk
        const bool act = (c4 < H);
        const bool isIH = (wid < 2);                  // waves 0/1 -> h0(t), waves 2/3 -> h1(t-1)
        const float* Wsel = isIH ? Wih1 : Whh1;

        v4f wv[16];
        #pragma unroll
        for (int r = 0; r < 16; ++r) {
            const int R_ = (r&3)*H + u0 + (r>>2);
            wv[r] = act ? *(const v4f*)(Wsel + (size_t)R_*H + c4) : v4z();
        }
        float bs = 0.f;
        if (wid == 0) { const int R_my = gate*H + u0 + unit; bs = bih1[R_my] + bhh1[R_my]; }

        float cs = 0.f;
        float* h0base = h0rep + (size_t)rep*K0*HP;
        float* h1base = h1rep + (size_t)rep*K1*HP;

        for (int t = 1; t <= T_STEPS; ++t) {
            const float s = isIH ? s0f(t) : s1f(t-1);
            const float* pm = isIH ? (h0base + (size_t)(t&(K0-1))*HP + c4)
                                   : (h1base + (size_t)((t-1)&(K1-1))*HP + c4);
            v4f Av = v4z(); bool gm = !act;
            while (!__all(gm)) {
                if (!gm) {
                    v4f a = pollx4(pm);
                    if (valid4(a, s)) { Av = a; gm = true; }
                }
            }
            v4f hd;
            hd.x = __builtin_fmaf(Av.x, s, -2.f); hd.y = __builtin_fmaf(Av.y, s, -2.f);
            hd.z = __builtin_fmaf(Av.z, s, -2.f); hd.w = __builtin_fmaf(Av.w, s, -2.f);

            float acc[16];
            #pragma unroll
            for (int r = 0; r < 16; ++r) acc[r] = dot4(wv[r], hd);

            float red = reduce16(acc, j);

            if (wid != 0) { if (j < 16) part[t&1][wid-1][j] = red; }
            __syncthreads();
            if (wid == 0) {
                float val = red + part[t&1][0][j&15] + part[t&1][1][j&15] + part[t&1][2][j&15] + bs;
                float hval = gates16(val, b2, b3, cs);
                if ((j & 60) == 0) {
                    const float sv = s1f(t);
                    const float outv = (hval + 2.f) * sv;
                    const size_t off = (size_t)(t&(K1-1))*HP + u0 + unit;
                    #pragma unroll
                    for (int rr = 0; rr < NREP; ++rr)
                        store1_cc(h1rep + (size_t)rr*K1*HP + off, outv);
                }
            }
        }

        // final FC on h1(T) by block g==0, wave 0 (no barriers past this point)
        if (g == 0 && wid == 0) {
            const int cA = 4*j, cB = 256 + 4*j;
            const bool hasB = (cB + 4 <= H);
            const float* hT = h1rep + (size_t)(T_STEPS&(K1-1))*HP;   // replica 0
            const float sfin = s1f(T_STEPS);                          // +1
            v4f Alat = v4z(), Blat = v4z(); bool ga = false, gb = !hasB;
            while (!__all(ga && gb)) {
                if (!(ga && gb)) {
                    v4f a, b;
                    pollx4_2(hT + cA, hT + cB, a, b);
                    if (!ga && valid4(a, sfin)) { Alat = a; ga = true; }
                    if (!gb && valid4(b, sfin)) { Blat = b; gb = true; }
                }
            }
            v4f v0, v1;
            v0.x=Alat.x-2.f; v0.y=Alat.y-2.f; v0.z=Alat.z-2.f; v0.w=Alat.w-2.f;
            v1.x=Blat.x-2.f; v1.y=Blat.y-2.f; v1.z=Blat.z-2.f; v1.w=Blat.w-2.f;
            if (!hasB) v1 = v4z();
            #pragma unroll 4
            for (int r = 0; r < NCLS; ++r) {
                const float* wr = fcW + (size_t)r*H;
                v4f fa = *(const v4f*)(wr + cA);
                v4f fb = hasB ? *(const v4f*)(wr + cB) : v4z();
                float a = dot4(fa, v0) + dot4(fb, v1);
                #pragma unroll
                for (int m = 32; m >= 1; m >>= 1) a += __shfl_xor(a, m, 64);
                if (j == 0) out[r] = a + fcb[r];
            }
        }
    }
}

extern "C" void kernel_launch(void* const* d_in, const int* in_sizes, int n_in,
                              void* d_out, int out_size, void* d_ws, size_t ws_size,
                              hipStream_t stream)
{
    const int*   seq  = (const int*)d_in[0];
    const float* emb  = (const float*)d_in[1];
    const float* Wih0 = (const float*)d_in[2];
    const float* Whh0 = (const float*)d_in[3];
    const float* bih0 = (const float*)d_in[4];
    const float* bhh0 = (const float*)d_in[5];
    const float* Wih1 = (const float*)d_in[6];
    const float* Whh1 = (const float*)d_in[7];
    const float* bih1 = (const float*)d_in[8];
    const float* bhh1 = (const float*)d_in[9];
    const float* fcW  = (const float*)d_in[10];
    const float* fcb  = (const float*)d_in[11];
    float* out = (float*)d_out;

    float* h0rep = (float*)d_ws;                       // [NREP][K0][HP]
    float* h1rep = h0rep + (size_t)NREP*K0*HP;         // [NREP][K1][HP]

    // init: NREP*K0*HP + NREP*K1*HP = 16384 + 8192 = 24576 floats = 96 blocks x 256
    hipLaunchKernelGGL(lstm_init, dim3(96), dim3(256), 0, stream, h0rep, h1rep);
    hipLaunchKernelGGL(lstm_main, dim3(NB0 + NB1), dim3(256), 0, stream,
                       seq, emb, Wih0, Whh0, bih0, bhh0, Wih1, Whh1, bih1, bhh1,
                       fcW, fcb, out, h0rep, h1rep);
}